// Round 2
// baseline (343.070 us; speedup 1.0000x reference)
//
#include <hip/hip_runtime.h>
#include <hip/hip_bf16.h>

typedef unsigned short u16;
typedef __bf16 bf16x8 __attribute__((ext_vector_type(8)));
typedef float f32x4 __attribute__((ext_vector_type(4)));

#define QSCALE (0.125f * 1.44269504088896340736f)   // hd^-0.5 * log2(e), folded into Q

__device__ __forceinline__ u16 f2bf(float f) {
    __hip_bfloat16 h = __float2bfloat16(f);
    return __builtin_bit_cast(u16, h);
}
__device__ __forceinline__ float bf2f(u16 u) {
    unsigned int x = ((unsigned int)u) << 16;
    return __builtin_bit_cast(float, x);
}
__device__ __forceinline__ bf16x8 ld_bf8(const u16* p) {
    uint4 u = *reinterpret_cast<const uint4*>(p);
    return __builtin_bit_cast(bf16x8, u);
}
__device__ __forceinline__ bf16x8 pack8f(f32x4 a, f32x4 b) {
    union { bf16x8 v; u16 u[8]; } r;
    #pragma unroll
    for (int i = 0; i < 4; i++) { r.u[i] = f2bf(a[i]); r.u[4+i] = f2bf(b[i]); }
    return r.v;
}
__device__ __forceinline__ bf16x8 pack8u(ushort4 a, ushort4 b) {
    union { bf16x8 v; ushort4 u[2]; } r;
    r.u[0] = a; r.u[1] = b;
    return r.v;
}

#define GLOAD_LDS16(g, l) __builtin_amdgcn_global_load_lds( \
    (const __attribute__((address_space(1))) unsigned int*)(g), \
    (__attribute__((address_space(3))) unsigned int*)(l), 16, 0, 0)

// ---------------------------------------------------------------- prep ----
__global__ __launch_bounds__(256) void prep_kernel(
    const float* __restrict__ x, const float* __restrict__ qkvw,
    const float* __restrict__ projw, const float* __restrict__ ts,
    const unsigned char* __restrict__ kpm,
    u16* __restrict__ Xb, u16* __restrict__ Wq, u16* __restrict__ Wp,
    float* __restrict__ logts)
{
    int i = blockIdx.x * 256 + threadIdx.x;
    const int XC = 4096 * 768;
    const int WQ = 2304 * 768;
    const int WP = 768 * 768;
    if (i < XC) { Xb[i] = f2bf(x[i]); return; }
    i -= XC;
    if (i < WQ) { Wq[i] = f2bf(qkvw[i]); return; }
    i -= WQ;
    if (i < WP) { Wp[i] = f2bf(projw[i]); return; }
    i -= WP;
    if (i < 2 * 2048) {
        float t = ts[i];
        logts[i] = (kpm[i] != 0) ? -1e30f : log2f(fmaxf(t, 1e-8f));
    }
}

// ---------------------------------------------------------------- GEMM ----
// C[m][n] = sum_k A[m][k]*Bm[n][k] (+bias). 128x128 tile, BK=32, 4 waves,
// global_load_lds width-16 staging (m97 pattern), linear LDS.
template<int EPI>
__global__ __launch_bounds__(256) void gemm_bt(
    const u16* __restrict__ A, const u16* __restrict__ Bm,
    const float* __restrict__ bias,
    u16* __restrict__ Qb, u16* __restrict__ Kb, u16* __restrict__ Vt,
    float* __restrict__ outp)
{
    __shared__ u16 As[128 * 32];
    __shared__ u16 Bs[128 * 32];
    const int K = 768;
    const int tid = threadIdx.x;
    const int m0 = blockIdx.y * 128;
    const int n0 = blockIdx.x * 128;
    const int w = tid >> 6, lane = tid & 63;
    const int wr = (w >> 1) * 64, wc = (w & 1) * 64;
    const int g = lane >> 4, l16 = lane & 15;

    // staging map: call c of wave w fills LDS u16 [(w*2+c)*512, +512)
    // lane i supplies row (w*2+c)*16 + (i>>2), kcols (i&3)*8 .. +8
    const int srow = lane >> 2;
    const int scol = (lane & 3) * 8;
    const u16* gA0 = A  + (size_t)(m0 + w*32      + srow) * K + scol;
    const u16* gA1 = A  + (size_t)(m0 + w*32 + 16 + srow) * K + scol;
    const u16* gB0 = Bm + (size_t)(n0 + w*32      + srow) * K + scol;
    const u16* gB1 = Bm + (size_t)(n0 + w*32 + 16 + srow) * K + scol;
    u16* lA0 = As + (w*2    ) * 512;
    u16* lA1 = As + (w*2 + 1) * 512;
    u16* lB0 = Bs + (w*2    ) * 512;
    u16* lB1 = Bs + (w*2 + 1) * 512;

    f32x4 acc[4][4] = {};
    for (int k0 = 0; k0 < K; k0 += 32) {
        __syncthreads();
        GLOAD_LDS16(gA0 + k0, lA0);
        GLOAD_LDS16(gA1 + k0, lA1);
        GLOAD_LDS16(gB0 + k0, lB0);
        GLOAD_LDS16(gB1 + k0, lB1);
        __syncthreads();
        bf16x8 af[4], bfr[4];
        #pragma unroll
        for (int i = 0; i < 4; i++) af[i]  = ld_bf8(&As[(wr + i*16 + l16)*32 + g*8]);
        #pragma unroll
        for (int j = 0; j < 4; j++) bfr[j] = ld_bf8(&Bs[(wc + j*16 + l16)*32 + g*8]);
        #pragma unroll
        for (int i = 0; i < 4; i++)
            #pragma unroll
            for (int j = 0; j < 4; j++)
                acc[i][j] = __builtin_amdgcn_mfma_f32_16x16x32_bf16(af[i], bfr[j], acc[i][j], 0, 0, 0);
    }

    #pragma unroll
    for (int j = 0; j < 4; j++) {
        const int n = n0 + wc + j*16 + l16;
        const float bs = bias[n];
        #pragma unroll
        for (int i = 0; i < 4; i++) {
            #pragma unroll
            for (int r = 0; r < 4; r++) {
                const int m = m0 + wr + i*16 + g*4 + r;   // C/D: row=4g+r, col=l16
                float v = acc[i][j][r] + bs;
                if (EPI == 0) {
                    int b = m >> 11, l = m & 2047;
                    unsigned int which = (unsigned int)n / 768u;
                    int rem = n - (int)which * 768;
                    int h = rem >> 6, d = rem & 63;
                    int bh = b * 12 + h;
                    if (which == 0)      Qb[((size_t)bh*2048 + l)*64 + d] = f2bf(v * QSCALE);
                    else if (which == 1) Kb[((size_t)bh*2048 + l)*64 + d] = f2bf(v);
                    else                 Vt[((size_t)bh*64 + d)*2048 + l] = f2bf(v);
                } else {
                    outp[(size_t)m * 768 + n] = v;
                }
            }
        }
    }
}

// ----------------------------------------------------------- attention ----
// Flash attention, swapped-operand form. One wave per 16 q-rows.
// S^T = mfma(K,Q): lane&15 = q, 4g+r (+16t) = key. Softmax nearly in-lane;
// P feeds PV's A-fragment directly (key-permutation matched on V loads).
__global__ __launch_bounds__(64) void attn_kernel(
    const u16* __restrict__ Q, const u16* __restrict__ Kb,
    const u16* __restrict__ Vt, const float* __restrict__ logts,
    u16* __restrict__ O)
{
    const int lane = threadIdx.x;
    const int g = lane >> 4, l16 = lane & 15;
    const int tile = 127 - blockIdx.x;          // largest work first
    const int bh = blockIdx.y;
    const int b = bh / 12, h = bh - b * 12;
    const int q0 = tile * 16;
    const int nkt = (tile >> 2) + 1;            // 64-key tiles, causal bound

    const u16* Qp = Q + ((size_t)bh * 2048 + q0) * 64;
    const u16* Kp = Kb + (size_t)bh * 2048 * 64;
    const u16* Vp = Vt + (size_t)bh * 64 * 2048;
    const float* lt = logts + b * 2048;

    const bf16x8 qf0 = ld_bf8(Qp + l16 * 64 + g * 8);
    const bf16x8 qf1 = ld_bf8(Qp + l16 * 64 + 32 + g * 8);

    f32x4 o[4] = {};
    float m = -1e30f, lp = 0.f;
    const int qmy = q0 + l16;                   // q-row this lane reduces

    for (int kt = 0; kt < nkt; kt++) {
        const int k0 = kt * 64;
        // ---- K fragments (A operand): row = key = k0+16t+l16 ----
        bf16x8 kf[4][2];
        #pragma unroll
        for (int t = 0; t < 4; t++) {
            const u16* kp = Kp + (size_t)(k0 + t*16 + l16) * 64 + g * 8;
            kf[t][0] = ld_bf8(kp);
            kf[t][1] = ld_bf8(kp + 32);
        }
        // ---- V loads (B operand, key-permuted to match P layout) ----
        ushort4 va[4][4];
        #pragma unroll
        for (int j = 0; j < 4; j++) {
            const u16* vp = Vp + (size_t)(j*16 + l16) * 2048 + k0 + 4*g;
            va[j][0] = *(const ushort4*)(vp);
            va[j][1] = *(const ushort4*)(vp + 16);
            va[j][2] = *(const ushort4*)(vp + 32);
            va[j][3] = *(const ushort4*)(vp + 48);
        }
        // ---- bias (log2 token sizes, padding folded in) ----
        f32x4 ltv[4];
        #pragma unroll
        for (int t = 0; t < 4; t++)
            ltv[t] = *(const f32x4*)(lt + k0 + t*16 + 4*g);
        // ---- S^T = K · Q^T ----
        f32x4 s[4];
        #pragma unroll
        for (int t = 0; t < 4; t++) {
            f32x4 z = {};
            z = __builtin_amdgcn_mfma_f32_16x16x32_bf16(kf[t][0], qf0, z, 0, 0, 0);
            z = __builtin_amdgcn_mfma_f32_16x16x32_bf16(kf[t][1], qf1, z, 0, 0, 0);
            s[t] = z;
        }
        // ---- mask + bias + per-q max (in-lane 16 + 2 shfl) ----
        float pmax = -1e30f;
        #pragma unroll
        for (int t = 0; t < 4; t++)
            #pragma unroll
            for (int r = 0; r < 4; r++) {
                const int key = k0 + t*16 + 4*g + r;
                float sv = (key <= qmy) ? s[t][r] + ltv[t][r] : -1e30f;
                s[t][r] = sv;
                pmax = fmaxf(pmax, sv);
            }
        pmax = fmaxf(pmax, __shfl_xor(pmax, 16));
        pmax = fmaxf(pmax, __shfl_xor(pmax, 32));
        // ---- online update, defer-max (THR=8 in log2 domain) ----
        if (!__all(pmax <= m + 8.f)) {
            const float mn = fmaxf(m, pmax);
            const float sc = __builtin_amdgcn_exp2f(m - mn);
            m = mn; lp *= sc;
            #pragma unroll
            for (int r = 0; r < 4; r++) {
                const float scr = __shfl(sc, (lane & 48) + 4*g + r);
                o[0][r] *= scr; o[1][r] *= scr; o[2][r] *= scr; o[3][r] *= scr;
            }
        }
        // ---- P = exp2(S-m); partial row-sums stay in-lane ----
        #pragma unroll
        for (int t = 0; t < 4; t++)
            #pragma unroll
            for (int r = 0; r < 4; r++) {
                const float p = __builtin_amdgcn_exp2f(s[t][r] - m);
                s[t][r] = p;
                lp += p;
            }
        const bf16x8 pa01 = pack8f(s[0], s[1]);
        const bf16x8 pa23 = pack8f(s[2], s[3]);
        // ---- O += P·V (key-permutation cancels between A and B) ----
        #pragma unroll
        for (int j = 0; j < 4; j++) {
            o[j] = __builtin_amdgcn_mfma_f32_16x16x32_bf16(pa01, pack8u(va[j][0], va[j][1]), o[j], 0, 0, 0);
            o[j] = __builtin_amdgcn_mfma_f32_16x16x32_bf16(pa23, pack8u(va[j][2], va[j][3]), o[j], 0, 0, 0);
        }
    }
    // ---- final: reduce l across groups, normalize, write ----
    lp += __shfl_xor(lp, 16);
    lp += __shfl_xor(lp, 32);
    const float rl = 1.f / lp;
    float rlr[4];
    #pragma unroll
    for (int r = 0; r < 4; r++) rlr[r] = __shfl(rl, (lane & 48) + 4*g + r);
    #pragma unroll
    for (int j = 0; j < 4; j++)
        #pragma unroll
        for (int r = 0; r < 4; r++) {
            const int q = q0 + 4*g + r;
            O[((size_t)b*2048 + q)*768 + h*64 + j*16 + l16] = f2bf(o[j][r] * rlr[r]);
        }
}

// ------------------------------------------------------------- k_merge ----
__global__ __launch_bounds__(256) void kmerge_kernel(
    const u16* __restrict__ Kb, float* __restrict__ out)
{
    const int idx = blockIdx.x * 256 + threadIdx.x;   // < 2*2048*64
    const int d = idx & 63, l = (idx >> 6) & 2047, b = idx >> 17;
    float s = 0.f;
    #pragma unroll
    for (int h = 0; h < 12; h++)
        s += bf2f(Kb[(((size_t)(b*12 + h))*2048 + l)*64 + d]);
    out[idx] = s * (1.f / 12.f);
}

// -------------------------------------------------------------- launch ----
extern "C" void kernel_launch(void* const* d_in, const int* in_sizes, int n_in,
                              void* d_out, int out_size, void* d_ws, size_t ws_size,
                              hipStream_t stream)
{
    const float* x     = (const float*)d_in[0];
    const float* ts    = (const float*)d_in[1];
    // d_in[2] = attn_mask (causal, hardcoded)
    const unsigned char* kpm = (const unsigned char*)d_in[3];
    const float* qkvw  = (const float*)d_in[4];
    const float* qkvb  = (const float*)d_in[5];
    const float* projw = (const float*)d_in[6];
    const float* projb = (const float*)d_in[7];
    float* out = (float*)d_out;

    char* ws = (char*)d_ws;
    u16* Xb = (u16*)ws;  ws += (size_t)4096 * 768 * 2;
    u16* Wq = (u16*)ws;  ws += (size_t)2304 * 768 * 2;
    u16* Wp = (u16*)ws;  ws += (size_t)768 * 768 * 2;
    u16* Qb = (u16*)ws;  ws += (size_t)24 * 2048 * 64 * 2;
    u16* Kb = (u16*)ws;  ws += (size_t)24 * 2048 * 64 * 2;
    u16* Vt = (u16*)ws;  ws += (size_t)24 * 2048 * 64 * 2;
    u16* Ob = (u16*)ws;  ws += (size_t)4096 * 768 * 2;
    float* logts = (float*)ws;

    const int prep_total = 4096*768 + 2304*768 + 768*768 + 2*2048;
    prep_kernel<<<(prep_total + 255) / 256, 256, 0, stream>>>(
        x, qkvw, projw, ts, kpm, Xb, Wq, Wp, logts);

    gemm_bt<0><<<dim3(18, 32), 256, 0, stream>>>(Xb, Wq, qkvb, Qb, Kb, Vt, nullptr);

    attn_kernel<<<dim3(128, 24), 64, 0, stream>>>(Qb, Kb, Vt, logts, Ob);

    kmerge_kernel<<<(2*2048*64) / 256, 256, 0, stream>>>(Kb, out + 3145728);

    gemm_bt<1><<<dim3(6, 32), 256, 0, stream>>>(Ob, Wp, projb, nullptr, nullptr, nullptr, out);
}

// Round 3
// 129.915 us; speedup vs baseline: 2.6407x; 2.6407x over previous
//
#include <hip/hip_runtime.h>
#include <hip/hip_bf16.h>

typedef unsigned short u16;
typedef __bf16 bf16x8 __attribute__((ext_vector_type(8)));
typedef float f32x4 __attribute__((ext_vector_type(4)));

#define QSCALE (0.125f * 1.44269504088896340736f)   // hd^-0.5 * log2(e), folded into Q

__device__ __forceinline__ u16 f2bf(float f) {
    __hip_bfloat16 h = __float2bfloat16(f);
    return __builtin_bit_cast(u16, h);
}
__device__ __forceinline__ float bf2f(u16 u) {
    unsigned int x = ((unsigned int)u) << 16;
    return __builtin_bit_cast(float, x);
}
__device__ __forceinline__ bf16x8 ld_bf8(const u16* p) {
    uint4 u = *reinterpret_cast<const uint4*>(p);
    return __builtin_bit_cast(bf16x8, u);
}
__device__ __forceinline__ bf16x8 pack8f(f32x4 a, f32x4 b) {
    union { bf16x8 v; u16 u[8]; } r;
    #pragma unroll
    for (int i = 0; i < 4; i++) { r.u[i] = f2bf(a[i]); r.u[4+i] = f2bf(b[i]); }
    return r.v;
}
__device__ __forceinline__ bf16x8 pack8u(ushort4 a, ushort4 b) {
    union { bf16x8 v; ushort4 u[2]; } r;
    r.u[0] = a; r.u[1] = b;
    return r.v;
}

#define GLOAD_LDS16(g, l) __builtin_amdgcn_global_load_lds( \
    (const __attribute__((address_space(1))) unsigned int*)(g), \
    (__attribute__((address_space(3))) unsigned int*)(l), 16, 0, 0)

// ---------------------------------------------------------------- prep ----
// float4-vectorized f32->bf16 conversion + log2(token_sizes) table.
__global__ __launch_bounds__(256) void prep_kernel(
    const float* __restrict__ x, const float* __restrict__ qkvw,
    const float* __restrict__ projw, const float* __restrict__ ts,
    const unsigned char* __restrict__ kpm,
    u16* __restrict__ Xb, u16* __restrict__ Wq, u16* __restrict__ Wp,
    float* __restrict__ logts)
{
    int i = blockIdx.x * 256 + threadIdx.x;
    const int XC4 = 4096 * 768 / 4;
    const int WQ4 = 2304 * 768 / 4;
    const int WP4 = 768 * 768 / 4;
    const float* src = nullptr; u16* dst = nullptr;
    if (i < XC4) { src = x; dst = Xb; }
    else {
        i -= XC4;
        if (i < WQ4) { src = qkvw; dst = Wq; }
        else {
            i -= WQ4;
            if (i < WP4) { src = projw; dst = Wp; }
            else {
                i -= WP4;
                if (i < 1024) {
                    float4 t = *(const float4*)(ts + i*4);
                    uchar4 k = *(const uchar4*)(kpm + i*4);
                    float4 r;
                    r.x = k.x ? -1e30f : log2f(fmaxf(t.x, 1e-8f));
                    r.y = k.y ? -1e30f : log2f(fmaxf(t.y, 1e-8f));
                    r.z = k.z ? -1e30f : log2f(fmaxf(t.z, 1e-8f));
                    r.w = k.w ? -1e30f : log2f(fmaxf(t.w, 1e-8f));
                    *(float4*)(logts + i*4) = r;
                }
                return;
            }
        }
    }
    float4 v = *(const float4*)(src + i*4);
    ushort4 o;
    o.x = f2bf(v.x); o.y = f2bf(v.y); o.z = f2bf(v.z); o.w = f2bf(v.w);
    *(ushort4*)(dst + i*4) = o;
}

// ---------------------------------------------------------------- GEMM ----
// C[m][n] = sum_k A[m][k]*Bm[n][k] (+bias). 128x128 tile, BK=32, 4 waves,
// global_load_lds width-16 staging, double-buffered (T3-minimum 2-phase).
template<int EPI>
__global__ __launch_bounds__(256) void gemm_bt(
    const u16* __restrict__ A, const u16* __restrict__ Bm,
    const float* __restrict__ bias,
    u16* __restrict__ Qb, u16* __restrict__ Kb, u16* __restrict__ Vt,
    float* __restrict__ outp)
{
    __shared__ u16 As[2][128 * 32];
    __shared__ u16 Bs[2][128 * 32];
    const int K = 768;
    const int tid = threadIdx.x;
    const int m0 = blockIdx.y * 128;
    const int n0 = blockIdx.x * 128;
    const int w = tid >> 6, lane = tid & 63;
    const int wr = (w >> 1) * 64, wc = (w & 1) * 64;
    const int g = lane >> 4, l16 = lane & 15;

    const int srow = lane >> 2;          // 0..15
    const int scol = (lane & 3) * 8;     // u16 col
    const u16* gA0 = A  + (size_t)(m0 + w*32      + srow) * K + scol;
    const u16* gA1 = A  + (size_t)(m0 + w*32 + 16 + srow) * K + scol;
    const u16* gB0 = Bm + (size_t)(n0 + w*32      + srow) * K + scol;
    const u16* gB1 = Bm + (size_t)(n0 + w*32 + 16 + srow) * K + scol;

#define GSTAGE(buf, kk) do { \
    GLOAD_LDS16(gA0 + (kk), &As[buf][(w*32     ) * 32]); \
    GLOAD_LDS16(gA1 + (kk), &As[buf][(w*32 + 16) * 32]); \
    GLOAD_LDS16(gB0 + (kk), &Bs[buf][(w*32     ) * 32]); \
    GLOAD_LDS16(gB1 + (kk), &Bs[buf][(w*32 + 16) * 32]); } while (0)

    f32x4 acc[4][4] = {};
    GSTAGE(0, 0);
    __syncthreads();
    for (int k0 = 0; k0 < K; k0 += 32) {
        const int cur = (k0 >> 5) & 1;
        if (k0 + 32 < K) GSTAGE(cur ^ 1, k0 + 32);
        bf16x8 af[4], bfr[4];
        #pragma unroll
        for (int i = 0; i < 4; i++) af[i]  = ld_bf8(&As[cur][(wr + i*16 + l16)*32 + g*8]);
        #pragma unroll
        for (int j = 0; j < 4; j++) bfr[j] = ld_bf8(&Bs[cur][(wc + j*16 + l16)*32 + g*8]);
        #pragma unroll
        for (int i = 0; i < 4; i++)
            #pragma unroll
            for (int j = 0; j < 4; j++)
                acc[i][j] = __builtin_amdgcn_mfma_f32_16x16x32_bf16(af[i], bfr[j], acc[i][j], 0, 0, 0);
        __syncthreads();
    }
#undef GSTAGE

    #pragma unroll
    for (int j = 0; j < 4; j++) {
        const int n = n0 + wc + j*16 + l16;
        const float bs = bias[n];
        #pragma unroll
        for (int i = 0; i < 4; i++) {
            #pragma unroll
            for (int r = 0; r < 4; r++) {
                const int m = m0 + wr + i*16 + g*4 + r;   // C/D: row=4g+r, col=l16
                float v = acc[i][j][r] + bs;
                if (EPI == 0) {
                    int b = m >> 11, l = m & 2047;
                    unsigned int which = (unsigned int)n / 768u;
                    int rem = n - (int)which * 768;
                    int h = rem >> 6, d = rem & 63;
                    int bh = b * 12 + h;
                    if (which == 0)      Qb[((size_t)bh*2048 + l)*64 + d] = f2bf(v * QSCALE);
                    else if (which == 1) Kb[((size_t)bh*2048 + l)*64 + d] = f2bf(v);
                    else                 Vt[((size_t)bh*64 + d)*2048 + l] = f2bf(v);
                } else {
                    outp[(size_t)m * 768 + n] = v;
                }
            }
        }
    }
}

// ----------------------------------------------------------- attention ----
// Flash attention, swapped-operand form. Block = 4 waves = 64 q-rows of one
// bh. K/V tiles (64 keys) staged in LDS via global_load_lds, double-buffered,
// XOR-swizzled both-sides (inverse-swizzled global source, swizzled reads).
__global__ __launch_bounds__(256) void attn_kernel(
    const u16* __restrict__ Q, const u16* __restrict__ Kb,
    const u16* __restrict__ Vt, const float* __restrict__ logts,
    u16* __restrict__ O)
{
    __shared__ u16 Ks[2][64 * 64];
    __shared__ u16 Vs[2][64 * 64];
    const int tid = threadIdx.x;
    const int w = tid >> 6, lane = tid & 63;
    const int g = lane >> 4, l16 = lane & 15;
    const int sw = l16 & 7;
    const int qt = 31 - (int)blockIdx.x;       // largest work first
    const int bh = blockIdx.y;
    const int b = bh / 12, h = bh - b * 12;
    const int q0 = qt * 64 + w * 16;           // this wave's 16 q-rows
    const int nkt = qt + 1;

    const u16* Qp = Q + ((size_t)bh * 2048 + q0) * 64;
    const u16* Kp = Kb + (size_t)bh * 2048 * 64;
    const u16* Vp = Vt + (size_t)bh * 64 * 2048;
    const float* lt = logts + b * 2048;

    // staging: lane -> row base+ (lane>>3), 16B slot (lane&7); source slot
    // inverse-swizzled so LDS content at (row, s) = logical slot s^(row&7).
    const int srow = lane >> 3;
    const int sslot = (lane & 7) ^ srow;
    const u16* gK0 = Kp + (size_t)(w*16 +     srow) * 64   + sslot * 8;
    const u16* gK1 = Kp + (size_t)(w*16 + 8 + srow) * 64   + sslot * 8;
    const u16* gV0 = Vp + (size_t)(w*16 +     srow) * 2048 + sslot * 8;
    const u16* gV1 = Vp + (size_t)(w*16 + 8 + srow) * 2048 + sslot * 8;

#define ASTAGE(buf, kk) do { \
    GLOAD_LDS16(gK0 + (size_t)(kk) * 64, &Ks[buf][(w*16    ) * 64]); \
    GLOAD_LDS16(gK1 + (size_t)(kk) * 64, &Ks[buf][(w*16 + 8) * 64]); \
    GLOAD_LDS16(gV0 + (kk),              &Vs[buf][(w*16    ) * 64]); \
    GLOAD_LDS16(gV1 + (kk),              &Vs[buf][(w*16 + 8) * 64]); } while (0)

    const bf16x8 qf0 = ld_bf8(Qp + l16 * 64 + g * 8);
    const bf16x8 qf1 = ld_bf8(Qp + l16 * 64 + 32 + g * 8);

    f32x4 o[4] = {};
    float m = -1e30f, lp = 0.f;
    const int qmy = q0 + l16;                  // q-row this lane reduces

    ASTAGE(0, 0);
    __syncthreads();

    for (int kt = 0; kt < nkt; kt++) {
        const int cur = kt & 1;
        const int k0 = kt * 64;
        if (kt + 1 < nkt) ASTAGE(cur ^ 1, k0 + 64);

        f32x4 ltv[4];
        #pragma unroll
        for (int t = 0; t < 4; t++)
            ltv[t] = *(const f32x4*)(lt + k0 + t*16 + 4*g);

        // ---- S^T = K · Q^T from swizzled LDS ----
        const int ko0 = 8 * (g ^ sw);
        f32x4 s[4];
        #pragma unroll
        for (int t = 0; t < 4; t++) {
            const u16* kb = &Ks[cur][(t*16 + l16) * 64];
            bf16x8 kf0 = ld_bf8(kb + ko0);
            bf16x8 kf1 = ld_bf8(kb + (ko0 ^ 32));
            f32x4 z = {};
            z = __builtin_amdgcn_mfma_f32_16x16x32_bf16(kf0, qf0, z, 0, 0, 0);
            z = __builtin_amdgcn_mfma_f32_16x16x32_bf16(kf1, qf1, z, 0, 0, 0);
            s[t] = z;
        }
        // ---- mask + bias + per-q max ----
        float pmax = -1e30f;
        #pragma unroll
        for (int t = 0; t < 4; t++)
            #pragma unroll
            for (int r = 0; r < 4; r++) {
                const int key = k0 + t*16 + 4*g + r;
                float sv = (key <= qmy) ? s[t][r] + ltv[t][r] : -1e30f;
                s[t][r] = sv;
                pmax = fmaxf(pmax, sv);
            }
        pmax = fmaxf(pmax, __shfl_xor(pmax, 16));
        pmax = fmaxf(pmax, __shfl_xor(pmax, 32));
        // ---- online update, defer-max (THR=8, log2 domain) ----
        if (!__all(pmax <= m + 8.f)) {
            const float mn = fmaxf(m, pmax);
            const float sc = __builtin_amdgcn_exp2f(m - mn);
            m = mn; lp *= sc;
            #pragma unroll
            for (int r = 0; r < 4; r++) {
                const float scr = __shfl(sc, (lane & 48) + 4*g + r);
                o[0][r] *= scr; o[1][r] *= scr; o[2][r] *= scr; o[3][r] *= scr;
            }
        }
        // ---- P = exp2(S-m) ----
        #pragma unroll
        for (int t = 0; t < 4; t++)
            #pragma unroll
            for (int r = 0; r < 4; r++) {
                const float p = __builtin_amdgcn_exp2f(s[t][r] - m);
                s[t][r] = p;
                lp += p;
            }
        const bf16x8 pa01 = pack8f(s[0], s[1]);
        const bf16x8 pa23 = pack8f(s[2], s[3]);
        // ---- O += P·V from swizzled LDS (key-perm cancels A vs B) ----
        const int gh = g >> 1, gl = 4 * (g & 1);
        #pragma unroll
        for (int j = 0; j < 4; j++) {
            const u16* vb = &Vs[cur][(j*16 + l16) * 64];
            ushort4 va0 = *(const ushort4*)(vb + (((0 + gh) ^ sw) << 3) + gl);
            ushort4 va1 = *(const ushort4*)(vb + (((2 + gh) ^ sw) << 3) + gl);
            ushort4 va2 = *(const ushort4*)(vb + (((4 + gh) ^ sw) << 3) + gl);
            ushort4 va3 = *(const ushort4*)(vb + (((6 + gh) ^ sw) << 3) + gl);
            o[j] = __builtin_amdgcn_mfma_f32_16x16x32_bf16(pa01, pack8u(va0, va1), o[j], 0, 0, 0);
            o[j] = __builtin_amdgcn_mfma_f32_16x16x32_bf16(pa23, pack8u(va2, va3), o[j], 0, 0, 0);
        }
        __syncthreads();
    }
#undef ASTAGE

    // ---- final: reduce l across groups, normalize, write ----
    lp += __shfl_xor(lp, 16);
    lp += __shfl_xor(lp, 32);
    const float rl = 1.f / lp;
    float rlr[4];
    #pragma unroll
    for (int r = 0; r < 4; r++) rlr[r] = __shfl(rl, (lane & 48) + 4*g + r);
    #pragma unroll
    for (int j = 0; j < 4; j++)
        #pragma unroll
        for (int r = 0; r < 4; r++) {
            const int q = q0 + 4*g + r;
            O[((size_t)b*2048 + q)*768 + h*64 + j*16 + l16] = f2bf(o[j][r] * rlr[r]);
        }
}

// ------------------------------------------------------------- k_merge ----
__global__ __launch_bounds__(256) void kmerge_kernel(
    const u16* __restrict__ Kb, float* __restrict__ out)
{
    const int idx = blockIdx.x * 256 + threadIdx.x;   // < 2*2048*16
    const int d4 = (idx & 15) * 4;
    const int l = (idx >> 4) & 2047;
    const int b = idx >> 15;
    float4 acc = {0.f, 0.f, 0.f, 0.f};
    #pragma unroll
    for (int h = 0; h < 12; h++) {
        ushort4 v = *(const ushort4*)&Kb[(((size_t)(b*12 + h))*2048 + l)*64 + d4];
        acc.x += bf2f(v.x); acc.y += bf2f(v.y);
        acc.z += bf2f(v.z); acc.w += bf2f(v.w);
    }
    const float s = 1.f / 12.f;
    float4 r = {acc.x * s, acc.y * s, acc.z * s, acc.w * s};
    *(float4*)&out[(((size_t)b*2048 + l))*64 + d4] = r;
}

// -------------------------------------------------------------- launch ----
extern "C" void kernel_launch(void* const* d_in, const int* in_sizes, int n_in,
                              void* d_out, int out_size, void* d_ws, size_t ws_size,
                              hipStream_t stream)
{
    const float* x     = (const float*)d_in[0];
    const float* ts    = (const float*)d_in[1];
    // d_in[2] = attn_mask (causal, hardcoded)
    const unsigned char* kpm = (const unsigned char*)d_in[3];
    const float* qkvw  = (const float*)d_in[4];
    const float* qkvb  = (const float*)d_in[5];
    const float* projw = (const float*)d_in[6];
    const float* projb = (const float*)d_in[7];
    float* out = (float*)d_out;

    char* ws = (char*)d_ws;
    u16* Xb = (u16*)ws;  ws += (size_t)4096 * 768 * 2;
    u16* Wq = (u16*)ws;  ws += (size_t)2304 * 768 * 2;
    u16* Wp = (u16*)ws;  ws += (size_t)768 * 768 * 2;
    u16* Qb = (u16*)ws;  ws += (size_t)24 * 2048 * 64 * 2;
    u16* Kb = (u16*)ws;  ws += (size_t)24 * 2048 * 64 * 2;
    u16* Vt = (u16*)ws;  ws += (size_t)24 * 2048 * 64 * 2;
    u16* Ob = (u16*)ws;  ws += (size_t)4096 * 768 * 2;
    float* logts = (float*)ws;

    const int prep4 = (4096*768 + 2304*768 + 768*768) / 4 + 1024;
    prep_kernel<<<(prep4 + 255) / 256, 256, 0, stream>>>(
        x, qkvw, projw, ts, kpm, Xb, Wq, Wp, logts);

    gemm_bt<0><<<dim3(18, 32), 256, 0, stream>>>(Xb, Wq, qkvb, Qb, Kb, Vt, nullptr);

    attn_kernel<<<dim3(32, 24), 256, 0, stream>>>(Qb, Kb, Vt, logts, Ob);

    kmerge_kernel<<<(2*2048*16) / 256, 256, 0, stream>>>(Kb, out + 3145728);

    gemm_bt<1><<<dim3(6, 32), 256, 0, stream>>>(Ob, Wp, projb, nullptr, nullptr, nullptr, out);
}

// Round 4
// 118.821 us; speedup vs baseline: 2.8873x; 1.0934x over previous
//
#include <hip/hip_runtime.h>
#include <hip/hip_bf16.h>

typedef unsigned short u16;
typedef __bf16 bf16x8 __attribute__((ext_vector_type(8)));
typedef float f32x4 __attribute__((ext_vector_type(4)));

#define QSCALE (0.125f * 1.44269504088896340736f)   // hd^-0.5 * log2(e), folded into Q

__device__ __forceinline__ u16 f2bf(float f) {
    __hip_bfloat16 h = __float2bfloat16(f);
    return __builtin_bit_cast(u16, h);
}
__device__ __forceinline__ float bf2f(u16 u) {
    unsigned int x = ((unsigned int)u) << 16;
    return __builtin_bit_cast(float, x);
}
__device__ __forceinline__ bf16x8 ld_bf8(const u16* p) {
    uint4 u = *reinterpret_cast<const uint4*>(p);
    return __builtin_bit_cast(bf16x8, u);
}
__device__ __forceinline__ bf16x8 pack8f(f32x4 a, f32x4 b) {
    union { bf16x8 v; u16 u[8]; } r;
    #pragma unroll
    for (int i = 0; i < 4; i++) { r.u[i] = f2bf(a[i]); r.u[4+i] = f2bf(b[i]); }
    return r.v;
}
__device__ __forceinline__ bf16x8 pack8u(ushort4 a, ushort4 b) {
    union { bf16x8 v; ushort4 u[2]; } r;
    r.u[0] = a; r.u[1] = b;
    return r.v;
}

#define GLOAD_LDS16(g, l) __builtin_amdgcn_global_load_lds( \
    (const __attribute__((address_space(1))) unsigned int*)(g), \
    (__attribute__((address_space(3))) unsigned int*)(l), 16, 0, 0)

// ---------------------------------------------------------------- prep ----
// float4-vectorized f32->bf16 conversion + clipped token-size weight table
// (0 where key_padding_mask) + zero the attention work-queue counter.
__global__ __launch_bounds__(256) void prep_kernel(
    const float* __restrict__ x, const float* __restrict__ qkvw,
    const float* __restrict__ projw, const float* __restrict__ ts,
    const unsigned char* __restrict__ kpm,
    u16* __restrict__ Xb, u16* __restrict__ Wq, u16* __restrict__ Wp,
    float* __restrict__ tsw, int* __restrict__ qcount)
{
    int i = blockIdx.x * 256 + threadIdx.x;
    if (i == 0) *qcount = 0;
    const int XC4 = 4096 * 768 / 4;
    const int WQ4 = 2304 * 768 / 4;
    const int WP4 = 768 * 768 / 4;
    const float* src = nullptr; u16* dst = nullptr;
    if (i < XC4) { src = x; dst = Xb; }
    else {
        i -= XC4;
        if (i < WQ4) { src = qkvw; dst = Wq; }
        else {
            i -= WQ4;
            if (i < WP4) { src = projw; dst = Wp; }
            else {
                i -= WP4;
                if (i < 1024) {
                    float4 t = *(const float4*)(ts + i*4);
                    uchar4 k = *(const uchar4*)(kpm + i*4);
                    float4 r;
                    r.x = k.x ? 0.f : fmaxf(t.x, 1e-8f);
                    r.y = k.y ? 0.f : fmaxf(t.y, 1e-8f);
                    r.z = k.z ? 0.f : fmaxf(t.z, 1e-8f);
                    r.w = k.w ? 0.f : fmaxf(t.w, 1e-8f);
                    *(float4*)(tsw + i*4) = r;
                }
                return;
            }
        }
    }
    float4 v = *(const float4*)(src + i*4);
    ushort4 o;
    o.x = f2bf(v.x); o.y = f2bf(v.y); o.z = f2bf(v.z); o.w = f2bf(v.w);
    *(ushort4*)(dst + i*4) = o;
}

// ---------------------------------------------------------------- GEMM ----
// C[m][n] = sum_k A[m][k]*Bm[n][k] (+bias). 128x128 tile, BK=32, 4 waves,
// global_load_lds width-16 staging, double-buffered.
template<int EPI>
__global__ __launch_bounds__(256) void gemm_bt(
    const u16* __restrict__ A, const u16* __restrict__ Bm,
    const float* __restrict__ bias,
    u16* __restrict__ Qb, u16* __restrict__ Kb, u16* __restrict__ Vt,
    float* __restrict__ outp)
{
    __shared__ u16 As[2][128 * 32];
    __shared__ u16 Bs[2][128 * 32];
    const int K = 768;
    const int tid = threadIdx.x;
    const int m0 = blockIdx.y * 128;
    const int n0 = blockIdx.x * 128;
    const int w = tid >> 6, lane = tid & 63;
    const int wr = (w >> 1) * 64, wc = (w & 1) * 64;
    const int g = lane >> 4, l16 = lane & 15;

    const int srow = lane >> 2;          // 0..15
    const int scol = (lane & 3) * 8;     // u16 col
    const u16* gA0 = A  + (size_t)(m0 + w*32      + srow) * K + scol;
    const u16* gA1 = A  + (size_t)(m0 + w*32 + 16 + srow) * K + scol;
    const u16* gB0 = Bm + (size_t)(n0 + w*32      + srow) * K + scol;
    const u16* gB1 = Bm + (size_t)(n0 + w*32 + 16 + srow) * K + scol;

#define GSTAGE(buf, kk) do { \
    GLOAD_LDS16(gA0 + (kk), &As[buf][(w*32     ) * 32]); \
    GLOAD_LDS16(gA1 + (kk), &As[buf][(w*32 + 16) * 32]); \
    GLOAD_LDS16(gB0 + (kk), &Bs[buf][(w*32     ) * 32]); \
    GLOAD_LDS16(gB1 + (kk), &Bs[buf][(w*32 + 16) * 32]); } while (0)

    f32x4 acc[4][4] = {};
    GSTAGE(0, 0);
    __syncthreads();
    for (int k0 = 0; k0 < K; k0 += 32) {
        const int cur = (k0 >> 5) & 1;
        if (k0 + 32 < K) GSTAGE(cur ^ 1, k0 + 32);
        bf16x8 af[4], bfr[4];
        #pragma unroll
        for (int i = 0; i < 4; i++) af[i]  = ld_bf8(&As[cur][(wr + i*16 + l16)*32 + g*8]);
        #pragma unroll
        for (int j = 0; j < 4; j++) bfr[j] = ld_bf8(&Bs[cur][(wc + j*16 + l16)*32 + g*8]);
        #pragma unroll
        for (int i = 0; i < 4; i++)
            #pragma unroll
            for (int j = 0; j < 4; j++)
                acc[i][j] = __builtin_amdgcn_mfma_f32_16x16x32_bf16(af[i], bfr[j], acc[i][j], 0, 0, 0);
        __syncthreads();
    }
#undef GSTAGE

    #pragma unroll
    for (int j = 0; j < 4; j++) {
        const int n = n0 + wc + j*16 + l16;
        const float bs = bias[n];
        #pragma unroll
        for (int i = 0; i < 4; i++) {
            #pragma unroll
            for (int r = 0; r < 4; r++) {
                const int m = m0 + wr + i*16 + g*4 + r;   // C/D: row=4g+r, col=l16
                float v = acc[i][j][r] + bs;
                if (EPI == 0) {
                    int b = m >> 11, l = m & 2047;
                    unsigned int which = (unsigned int)n / 768u;
                    int rem = n - (int)which * 768;
                    int h = rem >> 6, d = rem & 63;
                    int bh = b * 12 + h;
                    if (which == 0)      Qb[((size_t)bh*2048 + l)*64 + d] = f2bf(v * QSCALE);
                    else if (which == 1) Kb[((size_t)bh*2048 + l)*64 + d] = f2bf(v);
                    else                 Vt[((size_t)bh*64 + d)*2048 + l] = f2bf(v);
                } else {
                    outp[(size_t)m * 768 + n] = v;
                }
            }
        }
    }
}

// ----------------------------------------------------------- attention ----
// Persistent-block flash attention, swapped-operand form, atomic work queue.
// Item = (qt, bh): 64 q-rows, kt = 0..qt (causal). Items sorted largest-first.
// 4 waves/block, each owns 16 q-rows; K/V staged via global_load_lds,
// double-buffered, XOR-swizzled both-sides. Row-sum via MFMA (ones operand);
// token-size weights folded multiplicatively; mask only on diagonal tile.
__global__ __launch_bounds__(256, 2) void attn_kernel(
    const u16* __restrict__ Q, const u16* __restrict__ Kb,
    const u16* __restrict__ Vt, const float* __restrict__ tsw,
    u16* __restrict__ O, int* __restrict__ qcount)
{
    __shared__ u16 Ks[2][64 * 64];
    __shared__ u16 Vs[2][64 * 64];
    __shared__ int s_item;
    const int tid = threadIdx.x;
    const int w = tid >> 6, lane = tid & 63;
    const int g = lane >> 4, l16 = lane & 15;
    const int sw = l16 & 7;
    const int srow = lane >> 3;
    const int sslot = (lane & 7) ^ srow;

    bf16x8 ones;
    { union { bf16x8 v; u16 u[8]; } t;
      #pragma unroll
      for (int i = 0; i < 8; i++) t.u[i] = 0x3F80;  // bf16 1.0
      ones = t.v; }

    for (;;) {
        if (tid == 0) s_item = atomicAdd(qcount, 1);
        __syncthreads();
        const int item = s_item;
        if (item >= 768) return;
        const int qt = 31 - (item / 24);       // largest work first
        const int bh = item - (item / 24) * 24;
        const int b = bh / 12, h = bh - b * 12;
        const int q0 = qt * 64 + w * 16;       // this wave's 16 q-rows
        const int nkt = qt + 1;

        const u16* Qp = Q + ((size_t)bh * 2048 + q0) * 64;
        const u16* Kp = Kb + (size_t)bh * 2048 * 64;
        const u16* Vp = Vt + (size_t)bh * 64 * 2048;
        const float* tw = tsw + b * 2048;

        const u16* gK0 = Kp + (size_t)(w*16 +     srow) * 64   + sslot * 8;
        const u16* gK1 = Kp + (size_t)(w*16 + 8 + srow) * 64   + sslot * 8;
        const u16* gV0 = Vp + (size_t)(w*16 +     srow) * 2048 + sslot * 8;
        const u16* gV1 = Vp + (size_t)(w*16 + 8 + srow) * 2048 + sslot * 8;

#define ASTAGE(buf, kk) do { \
    GLOAD_LDS16(gK0 + (size_t)(kk) * 64, &Ks[buf][(w*16    ) * 64]); \
    GLOAD_LDS16(gK1 + (size_t)(kk) * 64, &Ks[buf][(w*16 + 8) * 64]); \
    GLOAD_LDS16(gV0 + (kk),              &Vs[buf][(w*16    ) * 64]); \
    GLOAD_LDS16(gV1 + (kk),              &Vs[buf][(w*16 + 8) * 64]); } while (0)

        const bf16x8 qf0 = ld_bf8(Qp + l16 * 64 + g * 8);
        const bf16x8 qf1 = ld_bf8(Qp + l16 * 64 + 32 + g * 8);

        f32x4 o[4] = {};
        f32x4 lpacc = {};
        float m = -1e30f;
        const int qmy = q0 + l16;              // q-row this lane reduces

        ASTAGE(0, 0);
        __syncthreads();

        for (int kt = 0; kt < nkt; kt++) {
            const int cur = kt & 1;
            const int k0 = kt * 64;
            if (kt + 1 < nkt) ASTAGE(cur ^ 1, k0 + 64);

            f32x4 twv[4];
            #pragma unroll
            for (int t = 0; t < 4; t++)
                twv[t] = *(const f32x4*)(tw + k0 + t*16 + 4*g);

            // ---- S^T = K · Q^T from swizzled LDS ----
            const int ko0 = 8 * (g ^ sw);
            f32x4 s[4];
            #pragma unroll
            for (int t = 0; t < 4; t++) {
                const u16* kb = &Ks[cur][(t*16 + l16) * 64];
                bf16x8 kf0 = ld_bf8(kb + ko0);
                bf16x8 kf1 = ld_bf8(kb + (ko0 ^ 32));
                f32x4 z = {};
                z = __builtin_amdgcn_mfma_f32_16x16x32_bf16(kf0, qf0, z, 0, 0, 0);
                z = __builtin_amdgcn_mfma_f32_16x16x32_bf16(kf1, qf1, z, 0, 0, 0);
                s[t] = z;
            }
            // ---- causal mask only on the diagonal tile (wave-uniform) ----
            if (kt == qt) {
                #pragma unroll
                for (int t = 0; t < 4; t++)
                    #pragma unroll
                    for (int r = 0; r < 4; r++) {
                        const int key = k0 + t*16 + 4*g + r;
                        if (key > qmy) s[t][r] = -1e30f;   // per-lane predicated
                    }
            }
            // ---- per-q max over raw s ----
            float pmax = -1e30f;
            #pragma unroll
            for (int t = 0; t < 4; t++)
                #pragma unroll
                for (int r = 0; r < 4; r++)
                    pmax = fmaxf(pmax, s[t][r]);
            pmax = fmaxf(pmax, __shfl_xor(pmax, 16));
            pmax = fmaxf(pmax, __shfl_xor(pmax, 32));
            // ---- online update, defer-max (THR=8, log2 domain) ----
            if (!__all(pmax <= m + 8.f)) {
                const float mn = fmaxf(m, pmax);
                const float sc = __builtin_amdgcn_exp2f(m - mn);
                m = mn;
                #pragma unroll
                for (int r = 0; r < 4; r++) {
                    const float scr = __shfl(sc, (lane & 48) + 4*g + r);
                    o[0][r] *= scr; o[1][r] *= scr; o[2][r] *= scr; o[3][r] *= scr;
                    lpacc[r] *= scr;
                }
            }
            // ---- P = exp2(s - m) * token_size ----
            #pragma unroll
            for (int t = 0; t < 4; t++)
                #pragma unroll
                for (int r = 0; r < 4; r++)
                    s[t][r] = __builtin_amdgcn_exp2f(s[t][r] - m) * twv[t][r];
            const bf16x8 pa01 = pack8f(s[0], s[1]);
            const bf16x8 pa23 = pack8f(s[2], s[3]);
            // ---- row-sums via MFMA (ones B); transforms exactly like o ----
            lpacc = __builtin_amdgcn_mfma_f32_16x16x32_bf16(pa01, ones, lpacc, 0, 0, 0);
            lpacc = __builtin_amdgcn_mfma_f32_16x16x32_bf16(pa23, ones, lpacc, 0, 0, 0);
            // ---- O += P·V from swizzled LDS (key-perm cancels A vs B) ----
            const int gh = g >> 1, gl = 4 * (g & 1);
            #pragma unroll
            for (int j = 0; j < 4; j++) {
                const u16* vb = &Vs[cur][(j*16 + l16) * 64];
                ushort4 va0 = *(const ushort4*)(vb + (((0 + gh) ^ sw) << 3) + gl);
                ushort4 va1 = *(const ushort4*)(vb + (((2 + gh) ^ sw) << 3) + gl);
                ushort4 va2 = *(const ushort4*)(vb + (((4 + gh) ^ sw) << 3) + gl);
                ushort4 va3 = *(const ushort4*)(vb + (((6 + gh) ^ sw) << 3) + gl);
                o[j] = __builtin_amdgcn_mfma_f32_16x16x32_bf16(pa01, pack8u(va0, va1), o[j], 0, 0, 0);
                o[j] = __builtin_amdgcn_mfma_f32_16x16x32_bf16(pa23, pack8u(va2, va3), o[j], 0, 0, 0);
            }
            __syncthreads();
        }
#undef ASTAGE

        // ---- normalize + write (lpacc[r] = row-sum for q-row 4g+r) ----
        float rlr[4];
        #pragma unroll
        for (int r = 0; r < 4; r++) rlr[r] = 1.f / lpacc[r];
        #pragma unroll
        for (int j = 0; j < 4; j++)
            #pragma unroll
            for (int r = 0; r < 4; r++) {
                const int q = q0 + 4*g + r;
                O[((size_t)b*2048 + q)*768 + h*64 + j*16 + l16] = f2bf(o[j][r] * rlr[r]);
            }
        // loop: grab next item (s_item rewrite guarded by the grab barrier)
    }
}

// ------------------------------------------------------------- k_merge ----
__global__ __launch_bounds__(256) void kmerge_kernel(
    const u16* __restrict__ Kb, float* __restrict__ out)
{
    const int idx = blockIdx.x * 256 + threadIdx.x;   // < 2*2048*16
    const int d4 = (idx & 15) * 4;
    const int l = (idx >> 4) & 2047;
    const int b = idx >> 15;
    float4 acc = {0.f, 0.f, 0.f, 0.f};
    #pragma unroll
    for (int h = 0; h < 12; h++) {
        ushort4 v = *(const ushort4*)&Kb[(((size_t)(b*12 + h))*2048 + l)*64 + d4];
        acc.x += bf2f(v.x); acc.y += bf2f(v.y);
        acc.z += bf2f(v.z); acc.w += bf2f(v.w);
    }
    const float s = 1.f / 12.f;
    float4 r = {acc.x * s, acc.y * s, acc.z * s, acc.w * s};
    *(float4*)&out[(((size_t)b*2048 + l))*64 + d4] = r;
}

// -------------------------------------------------------------- launch ----
extern "C" void kernel_launch(void* const* d_in, const int* in_sizes, int n_in,
                              void* d_out, int out_size, void* d_ws, size_t ws_size,
                              hipStream_t stream)
{
    const float* x     = (const float*)d_in[0];
    const float* ts    = (const float*)d_in[1];
    // d_in[2] = attn_mask (causal, hardcoded)
    const unsigned char* kpm = (const unsigned char*)d_in[3];
    const float* qkvw  = (const float*)d_in[4];
    const float* qkvb  = (const float*)d_in[5];
    const float* projw = (const float*)d_in[6];
    const float* projb = (const float*)d_in[7];
    float* out = (float*)d_out;

    char* ws = (char*)d_ws;
    u16* Xb = (u16*)ws;  ws += (size_t)4096 * 768 * 2;
    u16* Wq = (u16*)ws;  ws += (size_t)2304 * 768 * 2;
    u16* Wp = (u16*)ws;  ws += (size_t)768 * 768 * 2;
    u16* Qb = (u16*)ws;  ws += (size_t)24 * 2048 * 64 * 2;
    u16* Kb = (u16*)ws;  ws += (size_t)24 * 2048 * 64 * 2;
    u16* Vt = (u16*)ws;  ws += (size_t)24 * 2048 * 64 * 2;
    u16* Ob = (u16*)ws;  ws += (size_t)4096 * 768 * 2;
    float* tsw = (float*)ws;  ws += (size_t)2 * 2048 * 4;
    int* qcount = (int*)ws;

    const int prep4 = (4096*768 + 2304*768 + 768*768) / 4 + 1024;
    prep_kernel<<<(prep4 + 255) / 256, 256, 0, stream>>>(
        x, qkvw, projw, ts, kpm, Xb, Wq, Wp, tsw, qcount);

    gemm_bt<0><<<dim3(18, 32), 256, 0, stream>>>(Xb, Wq, qkvb, Qb, Kb, Vt, nullptr);

    attn_kernel<<<dim3(640), 256, 0, stream>>>(Qb, Kb, Vt, tsw, Ob, qcount);

    kmerge_kernel<<<(2*2048*16) / 256, 256, 0, stream>>>(Kb, out + 3145728);

    gemm_bt<1><<<dim3(6, 32), 256, 0, stream>>>(Ob, Wp, projb, nullptr, nullptr, nullptr, out);
}

// Round 5
// 110.670 us; speedup vs baseline: 3.0999x; 1.0736x over previous
//
#include <hip/hip_runtime.h>
#include <hip/hip_bf16.h>

typedef unsigned short u16;
typedef __bf16 bf16x8 __attribute__((ext_vector_type(8)));
typedef float f32x4 __attribute__((ext_vector_type(4)));

#define QSCALE (0.125f * 1.44269504088896340736f)   // hd^-0.5 * log2(e), folded into Q

__device__ __forceinline__ u16 f2bf(float f) {
    __hip_bfloat16 h = __float2bfloat16(f);
    return __builtin_bit_cast(u16, h);
}
__device__ __forceinline__ float bf2f(u16 u) {
    unsigned int x = ((unsigned int)u) << 16;
    return __builtin_bit_cast(float, x);
}
__device__ __forceinline__ bf16x8 ld_bf8(const u16* p) {
    uint4 u = *reinterpret_cast<const uint4*>(p);
    return __builtin_bit_cast(bf16x8, u);
}
__device__ __forceinline__ bf16x8 pack8f(f32x4 a, f32x4 b) {
    union { bf16x8 v; u16 u[8]; } r;
    #pragma unroll
    for (int i = 0; i < 4; i++) { r.u[i] = f2bf(a[i]); r.u[4+i] = f2bf(b[i]); }
    return r.v;
}
__device__ __forceinline__ bf16x8 pack8u(ushort4 a, ushort4 b) {
    union { bf16x8 v; ushort4 u[2]; } r;
    r.u[0] = a; r.u[1] = b;
    return r.v;
}

#define GLOAD_LDS16(g, l) __builtin_amdgcn_global_load_lds( \
    (const __attribute__((address_space(1))) unsigned int*)(g), \
    (__attribute__((address_space(3))) unsigned int*)(l), 16, 0, 0)

// ---------------------------------------------------------------- prep ----
// float4-vectorized f32->bf16 conversion; token-size weight tables
// (clipped, zeroed under key_padding_mask) in f32 (for V-prescale in gemm)
// and bf16 (for the attn denominator fragment); zero the work-queue counter.
__global__ __launch_bounds__(256) void prep_kernel(
    const float* __restrict__ x, const float* __restrict__ qkvw,
    const float* __restrict__ projw, const float* __restrict__ ts,
    const unsigned char* __restrict__ kpm,
    u16* __restrict__ Xb, u16* __restrict__ Wq, u16* __restrict__ Wp,
    float* __restrict__ tsw, u16* __restrict__ tbf, int* __restrict__ qcount)
{
    int i = blockIdx.x * 256 + threadIdx.x;
    if (i == 0) *qcount = 0;
    const int XC4 = 4096 * 768 / 4;
    const int WQ4 = 2304 * 768 / 4;
    const int WP4 = 768 * 768 / 4;
    const float* src = nullptr; u16* dst = nullptr;
    if (i < XC4) { src = x; dst = Xb; }
    else {
        i -= XC4;
        if (i < WQ4) { src = qkvw; dst = Wq; }
        else {
            i -= WQ4;
            if (i < WP4) { src = projw; dst = Wp; }
            else {
                i -= WP4;
                if (i < 1024) {
                    float4 t = *(const float4*)(ts + i*4);
                    uchar4 k = *(const uchar4*)(kpm + i*4);
                    float4 r;
                    r.x = k.x ? 0.f : fmaxf(t.x, 1e-8f);
                    r.y = k.y ? 0.f : fmaxf(t.y, 1e-8f);
                    r.z = k.z ? 0.f : fmaxf(t.z, 1e-8f);
                    r.w = k.w ? 0.f : fmaxf(t.w, 1e-8f);
                    *(float4*)(tsw + i*4) = r;
                    ushort4 o;
                    o.x = f2bf(r.x); o.y = f2bf(r.y);
                    o.z = f2bf(r.z); o.w = f2bf(r.w);
                    *(ushort4*)(tbf + i*4) = o;
                }
                return;
            }
        }
    }
    float4 v = *(const float4*)(src + i*4);
    ushort4 o;
    o.x = f2bf(v.x); o.y = f2bf(v.y); o.z = f2bf(v.z); o.w = f2bf(v.w);
    *(ushort4*)(dst + i*4) = o;
}

// ---------------------------------------------------------------- GEMM ----
// C[m][n] = sum_k A[m][k]*Bm[n][k] (+bias). 128x128 tile, BK=32, 4 waves,
// global_load_lds width-16 staging, double-buffered, XCD-swizzled grid.
// EPI==0 scatters Q (scaled), K, V^T (V prescaled by token-size weight).
template<int EPI>
__global__ __launch_bounds__(256) void gemm_bt(
    const u16* __restrict__ A, const u16* __restrict__ Bm,
    const float* __restrict__ bias, const float* __restrict__ tsw,
    u16* __restrict__ Qb, u16* __restrict__ Kb, u16* __restrict__ Vt,
    float* __restrict__ outp)
{
    __shared__ u16 As[2][128 * 32];
    __shared__ u16 Bs[2][128 * 32];
    const int K = 768;
    const int tid = threadIdx.x;
    // bijective XCD swizzle (nwg % 8 == 0 for both instantiations)
    const int nwg = gridDim.x * gridDim.y;
    const int flat = blockIdx.y * gridDim.x + blockIdx.x;
    const int per = nwg >> 3;
    const int swz = (flat & 7) * per + (flat >> 3);
    const int m0 = (swz / gridDim.x) * 128;
    const int n0 = (swz % gridDim.x) * 128;
    const int w = tid >> 6, lane = tid & 63;
    const int wr = (w >> 1) * 64, wc = (w & 1) * 64;
    const int g = lane >> 4, l16 = lane & 15;

    const int srow = lane >> 2;          // 0..15
    const int scol = (lane & 3) * 8;     // u16 col
    const u16* gA0 = A  + (size_t)(m0 + w*32      + srow) * K + scol;
    const u16* gA1 = A  + (size_t)(m0 + w*32 + 16 + srow) * K + scol;
    const u16* gB0 = Bm + (size_t)(n0 + w*32      + srow) * K + scol;
    const u16* gB1 = Bm + (size_t)(n0 + w*32 + 16 + srow) * K + scol;

#define GSTAGE(buf, kk) do { \
    GLOAD_LDS16(gA0 + (kk), &As[buf][(w*32     ) * 32]); \
    GLOAD_LDS16(gA1 + (kk), &As[buf][(w*32 + 16) * 32]); \
    GLOAD_LDS16(gB0 + (kk), &Bs[buf][(w*32     ) * 32]); \
    GLOAD_LDS16(gB1 + (kk), &Bs[buf][(w*32 + 16) * 32]); } while (0)

    f32x4 acc[4][4] = {};
    GSTAGE(0, 0);
    __syncthreads();
    for (int k0 = 0; k0 < K; k0 += 32) {
        const int cur = (k0 >> 5) & 1;
        if (k0 + 32 < K) GSTAGE(cur ^ 1, k0 + 32);
        bf16x8 af[4], bfr[4];
        #pragma unroll
        for (int i = 0; i < 4; i++) af[i]  = ld_bf8(&As[cur][(wr + i*16 + l16)*32 + g*8]);
        #pragma unroll
        for (int j = 0; j < 4; j++) bfr[j] = ld_bf8(&Bs[cur][(wc + j*16 + l16)*32 + g*8]);
        #pragma unroll
        for (int i = 0; i < 4; i++)
            #pragma unroll
            for (int j = 0; j < 4; j++)
                acc[i][j] = __builtin_amdgcn_mfma_f32_16x16x32_bf16(af[i], bfr[j], acc[i][j], 0, 0, 0);
        __syncthreads();
    }
#undef GSTAGE

    #pragma unroll
    for (int j = 0; j < 4; j++) {
        const int n = n0 + wc + j*16 + l16;
        const float bs = bias[n];
        #pragma unroll
        for (int i = 0; i < 4; i++) {
            #pragma unroll
            for (int r = 0; r < 4; r++) {
                const int m = m0 + wr + i*16 + g*4 + r;   // C/D: row=4g+r, col=l16
                float v = acc[i][j][r] + bs;
                if (EPI == 0) {
                    int b = m >> 11, l = m & 2047;
                    unsigned int which = (unsigned int)n / 768u;
                    int rem = n - (int)which * 768;
                    int h = rem >> 6, d = rem & 63;
                    int bh = b * 12 + h;
                    if (which == 0)      Qb[((size_t)bh*2048 + l)*64 + d] = f2bf(v * QSCALE);
                    else if (which == 1) Kb[((size_t)bh*2048 + l)*64 + d] = f2bf(v);
                    else                 Vt[((size_t)bh*64 + d)*2048 + l] = f2bf(v * tsw[b*2048 + l]);
                } else {
                    outp[(size_t)m * 768 + n] = v;
                }
            }
        }
    }
}

// ----------------------------------------------------------- attention ----
// Persistent-block flash attention, swapped-operand form, atomic work queue.
// V is prescaled by token-size weight; denominator = mfma(P, t_frag).
// All K/V LDS reads batch-issued right after the barrier (ILP); t-frag
// global loads issued BEFORE ASTAGE so softmax never waits on the stage
// (vmcnt drains in order).
__global__ __launch_bounds__(256, 2) void attn_kernel(
    const u16* __restrict__ Q, const u16* __restrict__ Kb,
    const u16* __restrict__ Vt, const u16* __restrict__ tbf,
    u16* __restrict__ O, int* __restrict__ qcount)
{
    __shared__ u16 Ks[2][64 * 64];
    __shared__ u16 Vs[2][64 * 64];
    __shared__ int s_item;
    const int tid = threadIdx.x;
    const int w = tid >> 6, lane = tid & 63;
    const int g = lane >> 4, l16 = lane & 15;
    const int sw = l16 & 7;
    const int srow = lane >> 3;
    const int sslot = (lane & 7) ^ srow;

    for (;;) {
        if (tid == 0) s_item = atomicAdd(qcount, 1);
        __syncthreads();
        const int item = s_item;
        if (item >= 768) return;
        const int qt = 31 - (item / 24);       // largest work first
        const int bh = item - (item / 24) * 24;
        const int b = bh / 12, h = bh - b * 12;
        const int q0 = qt * 64 + w * 16;       // this wave's 16 q-rows
        const int nkt = qt + 1;

        const u16* Qp = Q + ((size_t)bh * 2048 + q0) * 64;
        const u16* Kp = Kb + (size_t)bh * 2048 * 64;
        const u16* Vp = Vt + (size_t)bh * 64 * 2048;
        const u16* tb = tbf + b * 2048;

        const u16* gK0 = Kp + (size_t)(w*16 +     srow) * 64   + sslot * 8;
        const u16* gK1 = Kp + (size_t)(w*16 + 8 + srow) * 64   + sslot * 8;
        const u16* gV0 = Vp + (size_t)(w*16 +     srow) * 2048 + sslot * 8;
        const u16* gV1 = Vp + (size_t)(w*16 + 8 + srow) * 2048 + sslot * 8;

#define ASTAGE(buf, kk) do { \
    GLOAD_LDS16(gK0 + (size_t)(kk) * 64, &Ks[buf][(w*16    ) * 64]); \
    GLOAD_LDS16(gK1 + (size_t)(kk) * 64, &Ks[buf][(w*16 + 8) * 64]); \
    GLOAD_LDS16(gV0 + (kk),              &Vs[buf][(w*16    ) * 64]); \
    GLOAD_LDS16(gV1 + (kk),              &Vs[buf][(w*16 + 8) * 64]); } while (0)

        const bf16x8 qf0 = ld_bf8(Qp + l16 * 64 + g * 8);
        const bf16x8 qf1 = ld_bf8(Qp + l16 * 64 + 32 + g * 8);

        f32x4 o[4] = {};
        f32x4 lpacc = {};
        float m = -1e30f;
        const int qmy = q0 + l16;              // q-row this lane reduces

        ASTAGE(0, 0);
        __syncthreads();

        for (int kt = 0; kt < nkt; kt++) {
            const int cur = kt & 1;
            const int k0 = kt * 64;

            // ---- t-fragment loads FIRST (before ASTAGE: in-order vmcnt) ----
            const u16* tp = tb + k0 + 4*g;
            ushort4 t0 = *(const ushort4*)(tp);
            ushort4 t1 = *(const ushort4*)(tp + 16);
            ushort4 t2 = *(const ushort4*)(tp + 32);
            ushort4 t3 = *(const ushort4*)(tp + 48);

            if (kt + 1 < nkt) ASTAGE(cur ^ 1, k0 + 64);

            // ---- batch-issue ALL LDS reads (8 K b128 + 16 V b64) ----
            const int ko0 = 8 * (g ^ sw);
            bf16x8 kf[4][2];
            #pragma unroll
            for (int t = 0; t < 4; t++) {
                const u16* kb = &Ks[cur][(t*16 + l16) * 64];
                kf[t][0] = ld_bf8(kb + ko0);
                kf[t][1] = ld_bf8(kb + (ko0 ^ 32));
            }
            const int gh = g >> 1, gl = 4 * (g & 1);
            ushort4 va[4][4];
            #pragma unroll
            for (int j = 0; j < 4; j++) {
                const u16* vb = &Vs[cur][(j*16 + l16) * 64];
                va[j][0] = *(const ushort4*)(vb + (((0 + gh) ^ sw) << 3) + gl);
                va[j][1] = *(const ushort4*)(vb + (((2 + gh) ^ sw) << 3) + gl);
                va[j][2] = *(const ushort4*)(vb + (((4 + gh) ^ sw) << 3) + gl);
                va[j][3] = *(const ushort4*)(vb + (((6 + gh) ^ sw) << 3) + gl);
            }

            // ---- S^T = K · Q^T ----
            f32x4 s[4];
            #pragma unroll
            for (int t = 0; t < 4; t++) {
                f32x4 z = {};
                z = __builtin_amdgcn_mfma_f32_16x16x32_bf16(kf[t][0], qf0, z, 0, 0, 0);
                z = __builtin_amdgcn_mfma_f32_16x16x32_bf16(kf[t][1], qf1, z, 0, 0, 0);
                s[t] = z;
            }
            // ---- causal mask only on the diagonal tile (wave-uniform) ----
            if (kt == qt) {
                #pragma unroll
                for (int t = 0; t < 4; t++)
                    #pragma unroll
                    for (int r = 0; r < 4; r++) {
                        const int key = k0 + t*16 + 4*g + r;
                        if (key > qmy) s[t][r] = -1e30f;
                    }
            }
            // ---- per-q max ----
            float pmax = -1e30f;
            #pragma unroll
            for (int t = 0; t < 4; t++)
                #pragma unroll
                for (int r = 0; r < 4; r++)
                    pmax = fmaxf(pmax, s[t][r]);
            pmax = fmaxf(pmax, __shfl_xor(pmax, 16));
            pmax = fmaxf(pmax, __shfl_xor(pmax, 32));
            // ---- online update, defer-max (THR=8, log2 domain) ----
            if (!__all(pmax <= m + 8.f)) {
                const float mn = fmaxf(m, pmax);
                const float sc = __builtin_amdgcn_exp2f(m - mn);
                m = mn;
                #pragma unroll
                for (int r = 0; r < 4; r++) {
                    const float scr = __shfl(sc, (lane & 48) + 4*g + r);
                    o[0][r] *= scr; o[1][r] *= scr; o[2][r] *= scr; o[3][r] *= scr;
                    lpacc[r] *= scr;
                }
            }
            // ---- P = exp2(s - m) ----
            #pragma unroll
            for (int t = 0; t < 4; t++)
                #pragma unroll
                for (int r = 0; r < 4; r++)
                    s[t][r] = __builtin_amdgcn_exp2f(s[t][r] - m);
            const bf16x8 pa01 = pack8f(s[0], s[1]);
            const bf16x8 pa23 = pack8f(s[2], s[3]);
            // ---- denominator: Σ p·t via MFMA with t-fragment B ----
            lpacc = __builtin_amdgcn_mfma_f32_16x16x32_bf16(pa01, pack8u(t0, t1), lpacc, 0, 0, 0);
            lpacc = __builtin_amdgcn_mfma_f32_16x16x32_bf16(pa23, pack8u(t2, t3), lpacc, 0, 0, 0);
            // ---- O += P·V' (V prescaled by t; key-perm cancels A vs B) ----
            #pragma unroll
            for (int j = 0; j < 4; j++) {
                o[j] = __builtin_amdgcn_mfma_f32_16x16x32_bf16(pa01, pack8u(va[j][0], va[j][1]), o[j], 0, 0, 0);
                o[j] = __builtin_amdgcn_mfma_f32_16x16x32_bf16(pa23, pack8u(va[j][2], va[j][3]), o[j], 0, 0, 0);
            }
            __syncthreads();
        }
#undef ASTAGE

        // ---- normalize + write (lpacc[r] = Σ p·t for q-row 4g+r) ----
        float rlr[4];
        #pragma unroll
        for (int r = 0; r < 4; r++) rlr[r] = 1.f / lpacc[r];
        #pragma unroll
        for (int j = 0; j < 4; j++)
            #pragma unroll
            for (int r = 0; r < 4; r++) {
                const int q = q0 + 4*g + r;
                O[((size_t)b*2048 + q)*768 + h*64 + j*16 + l16] = f2bf(o[j][r] * rlr[r]);
            }
    }
}

// ------------------------------------------------------------- k_merge ----
__global__ __launch_bounds__(256) void kmerge_kernel(
    const u16* __restrict__ Kb, float* __restrict__ out)
{
    const int idx = blockIdx.x * 256 + threadIdx.x;   // < 2*2048*16
    const int d4 = (idx & 15) * 4;
    const int l = (idx >> 4) & 2047;
    const int b = idx >> 15;
    float4 acc = {0.f, 0.f, 0.f, 0.f};
    #pragma unroll
    for (int h = 0; h < 12; h++) {
        ushort4 v = *(const ushort4*)&Kb[(((size_t)(b*12 + h))*2048 + l)*64 + d4];
        acc.x += bf2f(v.x); acc.y += bf2f(v.y);
        acc.z += bf2f(v.z); acc.w += bf2f(v.w);
    }
    const float s = 1.f / 12.f;
    float4 r = {acc.x * s, acc.y * s, acc.z * s, acc.w * s};
    *(float4*)&out[(((size_t)b*2048 + l))*64 + d4] = r;
}

// -------------------------------------------------------------- launch ----
extern "C" void kernel_launch(void* const* d_in, const int* in_sizes, int n_in,
                              void* d_out, int out_size, void* d_ws, size_t ws_size,
                              hipStream_t stream)
{
    const float* x     = (const float*)d_in[0];
    const float* ts    = (const float*)d_in[1];
    // d_in[2] = attn_mask (causal, hardcoded)
    const unsigned char* kpm = (const unsigned char*)d_in[3];
    const float* qkvw  = (const float*)d_in[4];
    const float* qkvb  = (const float*)d_in[5];
    const float* projw = (const float*)d_in[6];
    const float* projb = (const float*)d_in[7];
    float* out = (float*)d_out;

    char* ws = (char*)d_ws;
    u16* Xb = (u16*)ws;  ws += (size_t)4096 * 768 * 2;
    u16* Wq = (u16*)ws;  ws += (size_t)2304 * 768 * 2;
    u16* Wp = (u16*)ws;  ws += (size_t)768 * 768 * 2;
    u16* Qb = (u16*)ws;  ws += (size_t)24 * 2048 * 64 * 2;
    u16* Kb = (u16*)ws;  ws += (size_t)24 * 2048 * 64 * 2;
    u16* Vt = (u16*)ws;  ws += (size_t)24 * 2048 * 64 * 2;
    u16* Ob = (u16*)ws;  ws += (size_t)4096 * 768 * 2;
    float* tsw = (float*)ws;  ws += (size_t)2 * 2048 * 4;
    u16* tbf = (u16*)ws;  ws += (size_t)2 * 2048 * 2;
    int* qcount = (int*)ws;

    const int prep4 = (4096*768 + 2304*768 + 768*768) / 4 + 1024;
    prep_kernel<<<(prep4 + 255) / 256, 256, 0, stream>>>(
        x, qkvw, projw, ts, kpm, Xb, Wq, Wp, tsw, tbf, qcount);

    gemm_bt<0><<<dim3(18, 32), 256, 0, stream>>>(Xb, Wq, qkvb, tsw, Qb, Kb, Vt, nullptr);

    attn_kernel<<<dim3(512), 256, 0, stream>>>(Qb, Kb, Vt, tbf, Ob, qcount);

    kmerge_kernel<<<(2*2048*16) / 256, 256, 0, stream>>>(Kb, out + 3145728);

    gemm_bt<1><<<dim3(6, 32), 256, 0, stream>>>(Ob, Wp, projb, nullptr, nullptr, nullptr, nullptr, out);
}